// Round 1
// baseline (1325.607 us; speedup 1.0000x reference)
//
#include <hip/hip_runtime.h>
#include <hip/hip_bf16.h>

// Sinkhorn normalization, N=8192, fp32.
// State is always s = s0 - a_i - b_j; only the two 8192-vectors are updated.
//   row: a_i = log sum_j exp(s0_ij - b_j)
//   col: b_j = log sum_i exp(s0_ij - a_i)
//   out: exp(s0_ij - a_i - b_j)

constexpr int N = 8192;
constexpr int NV4 = N / 4;            // 2048 float4 per row
constexpr int COL_CHUNKS = 128;       // row-chunks for column partial reduction
constexpr int ROWS_PER_CHUNK = N / COL_CHUNKS;  // 64

__device__ __forceinline__ float block_reduce_sum_256(float v) {
    // wave64 butterfly then cross-wave via LDS (4 waves)
    #pragma unroll
    for (int off = 32; off > 0; off >>= 1)
        v += __shfl_down(v, off, 64);
    __shared__ float smem[4];
    const int wave = threadIdx.x >> 6;
    if ((threadIdx.x & 63) == 0) smem[wave] = v;
    __syncthreads();
    if (threadIdx.x == 0) v = smem[0] + smem[1] + smem[2] + smem[3];
    return v;
}

// One block per row: a[row] = log sum_j exp(s0[row][j] - b[j])
__global__ __launch_bounds__(256) void row_lse(const float* __restrict__ s0,
                                               const float* __restrict__ b,
                                               float* __restrict__ a) {
    const int row = blockIdx.x;
    const float4* __restrict__ srow = (const float4*)(s0 + (size_t)row * N);
    const float4* __restrict__ b4 = (const float4*)b;
    float sum = 0.f;
    for (int k = threadIdx.x; k < NV4; k += 256) {
        float4 x = srow[k];
        float4 bb = b4[k];
        sum += __expf(x.x - bb.x);
        sum += __expf(x.y - bb.y);
        sum += __expf(x.z - bb.z);
        sum += __expf(x.w - bb.w);
    }
    sum = block_reduce_sum_256(sum);
    if (threadIdx.x == 0) a[row] = __logf(sum);
}

// grid (8, COL_CHUNKS): blockIdx.x tiles columns (1024 cols per block as float4),
// blockIdx.y picks the row chunk. part[chunk][j] = sum_{i in chunk} exp(s0_ij - a_i)
__global__ __launch_bounds__(256) void col_partial(const float* __restrict__ s0,
                                                   const float* __restrict__ a,
                                                   float* __restrict__ part) {
    const int col4 = blockIdx.x * 256 + threadIdx.x;  // float4 index, 0..2047
    const int row0 = blockIdx.y * ROWS_PER_CHUNK;
    const float4* __restrict__ s4 = (const float4*)s0;
    float4 sum = make_float4(0.f, 0.f, 0.f, 0.f);
    #pragma unroll 4
    for (int i = 0; i < ROWS_PER_CHUNK; ++i) {
        const int row = row0 + i;
        const float ai = a[row];
        float4 x = s4[(size_t)row * NV4 + col4];
        sum.x += __expf(x.x - ai);
        sum.y += __expf(x.y - ai);
        sum.z += __expf(x.z - ai);
        sum.w += __expf(x.w - ai);
    }
    ((float4*)part)[(size_t)blockIdx.y * NV4 + col4] = sum;
}

// b[j] = log sum_c part[c][j]
__global__ __launch_bounds__(256) void col_reduce(const float* __restrict__ part,
                                                  float* __restrict__ b) {
    const int j = blockIdx.x * 256 + threadIdx.x;  // 0..8191
    float sum = 0.f;
    #pragma unroll 8
    for (int c = 0; c < COL_CHUNKS; ++c)
        sum += part[(size_t)c * N + j];
    b[j] = __logf(sum);
}

// out = exp(s0 - a_i - b_j)
__global__ __launch_bounds__(256) void exp_out(const float* __restrict__ s0,
                                               const float* __restrict__ a,
                                               const float* __restrict__ b,
                                               float* __restrict__ out) {
    const int row = blockIdx.x;
    const float ai = a[row];
    const float4* __restrict__ srow = (const float4*)(s0 + (size_t)row * N);
    const float4* __restrict__ b4 = (const float4*)b;
    float4* __restrict__ orow = (float4*)(out + (size_t)row * N);
    for (int k = threadIdx.x; k < NV4; k += 256) {
        float4 x = srow[k];
        float4 bb = b4[k];
        float4 r;
        r.x = __expf(x.x - ai - bb.x);
        r.y = __expf(x.y - ai - bb.y);
        r.z = __expf(x.z - ai - bb.z);
        r.w = __expf(x.w - ai - bb.w);
        orow[k] = r;
    }
}

extern "C" void kernel_launch(void* const* d_in, const int* in_sizes, int n_in,
                              void* d_out, int out_size, void* d_ws, size_t ws_size,
                              hipStream_t stream) {
    const float* s0 = (const float*)d_in[0];
    float* out = (float*)d_out;

    float* a = (float*)d_ws;                 // 8192 floats
    float* b = a + N;                        // 8192 floats
    float* part = b + N;                     // COL_CHUNKS * 8192 floats = 4 MB

    // b starts at 0 (ws is poisoned 0xAA before every call)
    hipMemsetAsync(b, 0, N * sizeof(float), stream);

    for (int it = 0; it < 10; ++it) {
        row_lse<<<N, 256, 0, stream>>>(s0, b, a);
        col_partial<<<dim3(NV4 / 256, COL_CHUNKS), 256, 0, stream>>>(s0, a, part);
        col_reduce<<<N / 256, 256, 0, stream>>>(part, b);
    }
    exp_out<<<N, 256, 0, stream>>>(s0, a, b, out);
}

// Round 2
// 974.693 us; speedup vs baseline: 1.3600x; 1.3600x over previous
//
#include <hip/hip_runtime.h>
#include <hip/hip_bf16.h>

// Sinkhorn normalization, N=8192, fp32 in/out.
// Multiplicative-space formulation with fp16 E = exp(s0):
//   v_i = 1 / sum_j E_ij u_j        (row step;  v = e^{-a})
//   u_j = 1 / sum_i E_ij v_i        (col step;  u = e^{-b})
//   out = exp(s0_ij) * v_i * u_j    (final, fp32 exp for precision)
// E (128 MB fp16) lives in d_out (overwritten by final kernel last).
// d_ws holds v, u, and 4 MB of column partials (4.26 MB total).

constexpr int N = 8192;
constexpr int NV4 = N / 4;                       // 2048
constexpr int NV8 = N / 8;                       // 1024
constexpr int COL_CHUNKS = 128;
constexpr int ROWS_PER_CHUNK = N / COL_CHUNKS;   // 64

typedef _Float16 half8 __attribute__((ext_vector_type(8)));
typedef _Float16 half4 __attribute__((ext_vector_type(4)));

__device__ __forceinline__ float block_reduce_sum_256(float v) {
    #pragma unroll
    for (int off = 32; off > 0; off >>= 1)
        v += __shfl_down(v, off, 64);
    __shared__ float smem[4];
    const int wave = threadIdx.x >> 6;
    if ((threadIdx.x & 63) == 0) smem[wave] = v;
    __syncthreads();
    if (threadIdx.x == 0) v = smem[0] + smem[1] + smem[2] + smem[3];
    return v;
}

// One block per row: E[row][:] = exp(s0[row][:]) (fp16), v[row] = 1/rowsum.
// (First row step fused: u == 1 initially since b == 0.)
__global__ __launch_bounds__(256) void convert_rowsum(const float* __restrict__ s0,
                                                      _Float16* __restrict__ E,
                                                      float* __restrict__ v) {
    const int row = blockIdx.x;
    const float4* __restrict__ srow = (const float4*)(s0 + (size_t)row * N);
    half4* __restrict__ erow = (half4*)(E + (size_t)row * N);
    float sum = 0.f;
    for (int k = threadIdx.x; k < NV4; k += 256) {
        float4 x = srow[k];
        float e0 = __expf(x.x), e1 = __expf(x.y), e2 = __expf(x.z), e3 = __expf(x.w);
        half4 h;
        h[0] = (_Float16)e0; h[1] = (_Float16)e1; h[2] = (_Float16)e2; h[3] = (_Float16)e3;
        erow[k] = h;
        sum += e0 + e1 + e2 + e3;
    }
    sum = block_reduce_sum_256(sum);
    if (threadIdx.x == 0) v[row] = 1.f / sum;
}

// One block per row: v[row] = 1 / sum_j E[row][j] * u[j]
__global__ __launch_bounds__(256) void row_pass(const _Float16* __restrict__ E,
                                                const float* __restrict__ u,
                                                float* __restrict__ v) {
    const int row = blockIdx.x;
    const half8* __restrict__ erow = (const half8*)(E + (size_t)row * N);
    const float4* __restrict__ u4 = (const float4*)u;
    float sum = 0.f;
    for (int k = threadIdx.x; k < NV8; k += 256) {
        half8 e = erow[k];
        float4 ua = u4[2 * k], ub = u4[2 * k + 1];
        sum += (float)e[0] * ua.x + (float)e[1] * ua.y + (float)e[2] * ua.z + (float)e[3] * ua.w
             + (float)e[4] * ub.x + (float)e[5] * ub.y + (float)e[6] * ub.z + (float)e[7] * ub.w;
    }
    sum = block_reduce_sum_256(sum);
    if (threadIdx.x == 0) v[row] = 1.f / sum;
}

// grid (NV8/256=4, COL_CHUNKS): part[chunk][j] = sum_{i in chunk} E_ij * v_i
__global__ __launch_bounds__(256) void col_partial(const _Float16* __restrict__ E,
                                                   const float* __restrict__ v,
                                                   float* __restrict__ part) {
    const int j8 = blockIdx.x * 256 + threadIdx.x;   // half8 column index, 0..1023
    const int row0 = blockIdx.y * ROWS_PER_CHUNK;
    const half8* __restrict__ e8 = (const half8*)E;
    float sum[8];
    #pragma unroll
    for (int k = 0; k < 8; ++k) sum[k] = 0.f;
    #pragma unroll 4
    for (int i = 0; i < ROWS_PER_CHUNK; ++i) {
        const int row = row0 + i;
        const float vi = v[row];
        half8 e = e8[(size_t)row * NV8 + j8];
        #pragma unroll
        for (int k = 0; k < 8; ++k) sum[k] += vi * (float)e[k];
    }
    float4* __restrict__ p4 = (float4*)(part + (size_t)blockIdx.y * N);
    p4[2 * j8]     = make_float4(sum[0], sum[1], sum[2], sum[3]);
    p4[2 * j8 + 1] = make_float4(sum[4], sum[5], sum[6], sum[7]);
}

// u[j] = 1 / sum_c part[c][j]
__global__ __launch_bounds__(256) void col_reduce(const float* __restrict__ part,
                                                  float* __restrict__ u) {
    const int j = blockIdx.x * 256 + threadIdx.x;
    float sum = 0.f;
    #pragma unroll 8
    for (int c = 0; c < COL_CHUNKS; ++c)
        sum += part[(size_t)c * N + j];
    u[j] = 1.f / sum;
}

// out = exp(s0_ij) * v_i * u_j  (fp32 path; overwrites the E scratch in d_out)
__global__ __launch_bounds__(256) void final_out(const float* __restrict__ s0,
                                                 const float* __restrict__ v,
                                                 const float* __restrict__ u,
                                                 float* __restrict__ out) {
    const int row = blockIdx.x;
    const float vi = v[row];
    const float4* __restrict__ srow = (const float4*)(s0 + (size_t)row * N);
    const float4* __restrict__ u4 = (const float4*)u;
    float4* __restrict__ orow = (float4*)(out + (size_t)row * N);
    for (int k = threadIdx.x; k < NV4; k += 256) {
        float4 x = srow[k];
        float4 uu = u4[k];
        float4 r;
        r.x = __expf(x.x) * vi * uu.x;
        r.y = __expf(x.y) * vi * uu.y;
        r.z = __expf(x.z) * vi * uu.z;
        r.w = __expf(x.w) * vi * uu.w;
        orow[k] = r;
    }
}

extern "C" void kernel_launch(void* const* d_in, const int* in_sizes, int n_in,
                              void* d_out, int out_size, void* d_ws, size_t ws_size,
                              hipStream_t stream) {
    const float* s0 = (const float*)d_in[0];
    float* out = (float*)d_out;

    _Float16* E = (_Float16*)d_out;          // 128 MB scratch inside the 256 MB output buffer
    float* v = (float*)d_ws;                 // 8192 floats
    float* u = v + N;                        // 8192 floats
    float* part = u + N;                     // COL_CHUNKS * 8192 floats = 4 MB

    convert_rowsum<<<N, 256, 0, stream>>>(s0, E, v);   // fused row step #1 (u == 1)
    for (int it = 0; it < 10; ++it) {
        if (it > 0)
            row_pass<<<N, 256, 0, stream>>>(E, u, v);
        col_partial<<<dim3(NV8 / 256, COL_CHUNKS), 256, 0, stream>>>(E, v, part);
        col_reduce<<<N / 256, 256, 0, stream>>>(part, u);
    }
    final_out<<<N, 256, 0, stream>>>(s0, v, u, out);
}